// Round 13
// baseline (267.379 us; speedup 1.0000x reference)
//
#include <hip/hip_runtime.h>

typedef unsigned short u16;
typedef unsigned int   u32;
typedef __attribute__((ext_vector_type(4))) float fx4;
typedef __attribute__((ext_vector_type(8))) __bf16 bf16x8;
typedef __attribute__((ext_vector_type(8))) unsigned short us8;
typedef __attribute__((ext_vector_type(2))) unsigned int u32x2;

__device__ __forceinline__ u16 f2bf(float x){
  u32 u = __builtin_bit_cast(u32, x);
  u += 0x7fffu + ((u >> 16) & 1u);
  return (u16)(u >> 16);
}
__device__ __forceinline__ float b2f(u16 h){
  u32 u = ((u32)h) << 16;
  return __builtin_bit_cast(float, u);
}
__device__ __forceinline__ void gld16(const void* g, void* l){
  __builtin_amdgcn_global_load_lds(
      (const __attribute__((address_space(1))) u32*)g,
      (__attribute__((address_space(3))) u32*)l, 16, 0, 0);
}
// XCD-chunked bijective swizzle (grid size must be %8==0).
__device__ __forceinline__ void xcd_remap(u32& bx, u32& by, u32& bz){
  u32 nx = gridDim.x, ny = gridDim.y, nz = gridDim.z;
  u32 nwg = nx * ny * nz;
  u32 orig = (blockIdx.z * ny + blockIdx.y) * nx + blockIdx.x;
  u32 lid = (orig & 7u) * (nwg >> 3) + (orig >> 3);
  bx = lid % nx;
  u32 rem = lid / nx;
  by = rem % ny;
  bz = rem / ny;
}

// ---------------- fp32 -> bf16 convert: 4 weights + q in ONE launch -------------
// y 0..3 -> weight y ; y 4..19 -> q slab (y-4). Also zeroes the 256-float colsum.
__global__ __launch_bounds__(256) void k_f2bfAll(const float* __restrict__ w0,
                                                 const float* __restrict__ w1,
                                                 const float* __restrict__ w2,
                                                 const float* __restrict__ w3,
                                                 const float* __restrict__ q,
                                                 u16* __restrict__ wout,
                                                 u16* __restrict__ qout,
                                                 float* __restrict__ zbuf){
  if (blockIdx.x == 0 && blockIdx.y == 0) zbuf[threadIdx.x] = 0.f;
  const int y = blockIdx.y;
  const float* src;
  u16* dst;
  if (y < 4){
    src = y == 0 ? w0 : y == 1 ? w1 : y == 2 ? w2 : w3;
    dst = wout + (long)y * 1048576;
  } else {
    src = q + (long)(y - 4) * 1048576;
    dst = qout + (long)(y - 4) * 1048576;
  }
  int i = blockIdx.x * 256 + threadIdx.x;
  const int stride = gridDim.x * 256;
  for (; i < 131072; i += stride){
    const float4* p = (const float4*)src + (long)i * 2;
    float4 a = p[0], b = p[1];
    us8 o = { f2bf(a.x), f2bf(a.y), f2bf(a.z), f2bf(a.w),
              f2bf(b.x), f2bf(b.y), f2bf(b.z), f2bf(b.w) };
    *((us8*)dst + i) = o;
  }
}

// ---------------- k/v transpose+convert v2: register 4x4 transpose, no LDS ------
// [2048 n][1024 d] f32 -> [1024 d][2048 n] bf16. z 0..7 k batch, 8..15 v batch.
// Thread loads a 4x4 fp32 block as 4x float4 (coalesced 256B segs), transposes in
// registers, stores 4x 8B bf16 column-vectors; per (oc,block) the j-stores complete
// 128B contiguous -> L2 write-combines to full lines.
__global__ __launch_bounds__(256) void k_tconvKV(const float* __restrict__ ksrc,
                                                 const float* __restrict__ vsrc,
                                                 u16* __restrict__ kT){
  const int z = blockIdx.z;
  const float* in = (z >= 8 ? vsrc : ksrc) + (long)(z & 7) * 2097152;
  u16* out = kT + (long)(z >> 3) * 16777216 + (long)(z & 7) * 2097152;
  const int c0 = blockIdx.x * 64, r0 = blockIdx.y * 64;
  const int t = threadIdx.x;
  const int c4 = t & 15, r4 = t >> 4;        // col group (4 cols), row group (4 rows)
  float4 f[4];
  #pragma unroll
  for (int i = 0; i < 4; ++i)
    f[i] = *(const float4*)(in + (long)(r0 + r4 * 4 + i) * 1024 + c0 + c4 * 4);
  #pragma unroll
  for (int j = 0; j < 4; ++j){
    u32 lo = (u32)f2bf(((const float*)&f[0])[j]) | ((u32)f2bf(((const float*)&f[1])[j]) << 16);
    u32 hi = (u32)f2bf(((const float*)&f[2])[j]) | ((u32)f2bf(((const float*)&f[3])[j]) << 16);
    u32x2 pr = { lo, hi };
    *(u32x2*)(out + (long)(c0 + c4 * 4 + j) * 2048 + r0 + r4 * 4) = pr;
  }
}

// ---------------- proj transpose+convert+colsum, one launch (z 0..1) ----------------
__global__ __launch_bounds__(256) void k_tconvP(const float* __restrict__ pjk,
                                                const float* __restrict__ pjv,
                                                u16* __restrict__ projT,
                                                float* __restrict__ ssum){
  const int z = blockIdx.z;
  const float* in = z ? pjv : pjk;
  u16* out = projT + z * 262144;
  float* colsum = ssum + z * 128;
  const int c0 = blockIdx.x * 64, r0 = blockIdx.y * 64;
  __shared__ u16 tile[64][66];
  __shared__ float red[256];
  const int t = threadIdx.x;
  const int cc = t & 63, wq = t >> 6;
  float part = 0.f;
  #pragma unroll
  for (int i = 0; i < 16; ++i){
    int rr = i * 4 + wq;
    float v = in[(long)(r0 + rr) * 128 + c0 + cc];
    tile[rr][cc] = f2bf(v);
    part += v;
  }
  red[t] = part;
  __syncthreads();
  if (t < 64){
    float s = red[t] + red[t + 64] + red[t + 128] + red[t + 192];
    atomicAdd(&colsum[c0 + t], s);
  }
  __syncthreads();
  const int oc0 = t >> 5, jb = (t & 31) * 2;
  #pragma unroll
  for (int i = 0; i < 8; ++i){
    int oc = oc0 + i * 8;
    u32 pk2 = (u32)tile[jb][oc] | ((u32)tile[jb + 1][oc] << 16);
    *(u32*)(out + (long)(c0 + oc) * 2048 + r0 + jb) = pk2;
  }
}

// ---------------- BT-layout MFMA GEMM (small/batched shapes) ----------------
// MODE 0: z-batch via strides.  MODE 3: ck/cv combined (projT x kT/vT).
template<int BM, int BN, int MODE, int EPI, typename OutT>
__global__ __launch_bounds__(256) void k_gemm(
    const u16* __restrict__ A, int lda, long sAz,
    const u16* __restrict__ B, int ldb, long sBz,
    OutT* __restrict__ C, int ldc, long sCz,
    int K, const float* __restrict__ bias, const float* __restrict__ srow, float scale)
{
  constexpr int BK = 64;
  constexpr int FM = BM / 32, FN = BN / 32;
  __shared__ u16 ldsA[BM * BK];
  __shared__ u16 ldsB[BN * BK];
  u32 bx, by, bz;
  xcd_remap(bx, by, bz);
  const long z = bz;
  if constexpr (MODE == 0){ A += z * sAz; B += z * sBz; C += z * sCz; }
  if constexpr (MODE == 3){ long p = z >> 3, bb = z & 7;
                            A += p * 262144; B += p * 16777216 + bb * 2097152;
                            C += p * 1048576 + bb * 131072; }
  const int t = threadIdx.x;
  const int lane = t & 63;
  const int w = t >> 6, wm = w >> 1, wn = w & 1;
  const int r15 = lane & 15, g = lane >> 4;
  const int m0 = by * BM, n0 = bx * BN;
  fx4 acc[FM][FN] = {};
  constexpr int CA = BM * BK / (8 * 256);
  constexpr int CB = BN * BK / (8 * 256);
  for (int kt = 0; kt < K; kt += BK){
    #pragma unroll
    for (int i = 0; i < CA; ++i){
      int ch = i * 256 + t, row = ch >> 3, cc = ch & 7;
      gld16(A + (long)(m0 + row) * lda + kt + cc * 8, (char*)ldsA + ch * 16);
    }
    #pragma unroll
    for (int i = 0; i < CB; ++i){
      int ch = i * 256 + t, row = ch >> 3, cc = ch & 7;
      gld16(B + (long)(n0 + row) * ldb + kt + cc * 8, (char*)ldsB + ch * 16);
    }
    __syncthreads();
    #pragma unroll
    for (int ks = 0; ks < 2; ++ks){
      bf16x8 af[FM], bfv[FN];
      #pragma unroll
      for (int mf = 0; mf < FM; ++mf)
        af[mf] = *(const bf16x8*)&ldsA[(wm * (BM/2) + mf * 16 + r15) * BK + ks * 32 + g * 8];
      #pragma unroll
      for (int nf = 0; nf < FN; ++nf)
        bfv[nf] = *(const bf16x8*)&ldsB[(wn * (BN/2) + nf * 16 + r15) * BK + ks * 32 + g * 8];
      #pragma unroll
      for (int mf = 0; mf < FM; ++mf)
        #pragma unroll
        for (int nf = 0; nf < FN; ++nf)
          acc[mf][nf] = __builtin_amdgcn_mfma_f32_16x16x32_bf16(af[mf], bfv[nf], acc[mf][nf], 0, 0, 0);
    }
    __syncthreads();
  }
  #pragma unroll
  for (int mf = 0; mf < FM; ++mf){
    #pragma unroll
    for (int nf = 0; nf < FN; ++nf){
      const int row0 = m0 + wm * (BM/2) + mf * 16 + g * 4;
      const int col  = n0 + wn * (BN/2) + nf * 16 + r15;
      float vv[4];
      #pragma unroll
      for (int r = 0; r < 4; ++r){
        float v = acc[mf][nf][r];
        if constexpr (EPI == 1) v += bias[col];
        vv[r] = v;
      }
      #pragma unroll
      for (int r = 0; r < 4; ++r){
        if constexpr (sizeof(OutT) == 2) C[(long)(row0 + r) * ldc + col] = (OutT)f2bf(vv[r]);
        else                             C[(long)(row0 + r) * ldc + col] = (OutT)vv[r];
      }
    }
  }
}

// ---------------- merged pk / pvT GEMM (z<8: pk EPI2 ; z>=8: pvT EPI3) ----------------
__global__ __launch_bounds__(256) void k_pkpv(
    const u16* __restrict__ ck, const u16* __restrict__ Wk_bf,
    const u16* __restrict__ Wv_bf, const float* __restrict__ bk,
    const float* __restrict__ bv, const float* __restrict__ ssum,
    u16* __restrict__ pk, u16* __restrict__ pvT)
{
  constexpr int BM = 64, BN = 64, BK = 64;
  __shared__ u16 ldsA[BM * BK];
  __shared__ u16 ldsB[BN * BK];
  u32 bx, by, bz;
  xcd_remap(bx, by, bz);
  const int half = bz >> 3, b = bz & 7;
  const u16* A = ck + half * 1048576 + b * 131072;
  const u16* B = half ? Wv_bf : Wk_bf;
  const float* bias = half ? bv : bk;
  const float* srow = ssum + half * 128;
  const float scale = half ? 1.f : 0.125f;
  const int t = threadIdx.x;
  const int lane = t & 63;
  const int w = t >> 6, wm = w >> 1, wn = w & 1;
  const int r15 = lane & 15, g = lane >> 4;
  const int m0 = by * BM, n0 = bx * BN;
  fx4 acc[2][2] = {};
  for (int kt = 0; kt < 1024; kt += BK){
    #pragma unroll
    for (int i = 0; i < 2; ++i){
      int ch = i * 256 + t, row = ch >> 3, cc = ch & 7;
      gld16(A + (long)(m0 + row) * 1024 + kt + cc * 8, (char*)ldsA + ch * 16);
    }
    #pragma unroll
    for (int i = 0; i < 2; ++i){
      int ch = i * 256 + t, row = ch >> 3, cc = ch & 7;
      gld16(B + (long)(n0 + row) * 1024 + kt + cc * 8, (char*)ldsB + ch * 16);
    }
    __syncthreads();
    #pragma unroll
    for (int ks = 0; ks < 2; ++ks){
      bf16x8 af[2], bfv[2];
      #pragma unroll
      for (int mf = 0; mf < 2; ++mf)
        af[mf] = *(const bf16x8*)&ldsA[(wm * 32 + mf * 16 + r15) * BK + ks * 32 + g * 8];
      #pragma unroll
      for (int nf = 0; nf < 2; ++nf)
        bfv[nf] = *(const bf16x8*)&ldsB[(wn * 32 + nf * 16 + r15) * BK + ks * 32 + g * 8];
      #pragma unroll
      for (int mf = 0; mf < 2; ++mf)
        #pragma unroll
        for (int nf = 0; nf < 2; ++nf)
          acc[mf][nf] = __builtin_amdgcn_mfma_f32_16x16x32_bf16(af[mf], bfv[nf], acc[mf][nf], 0, 0, 0);
    }
    __syncthreads();
  }
  #pragma unroll
  for (int mf = 0; mf < 2; ++mf){
    #pragma unroll
    for (int nf = 0; nf < 2; ++nf){
      const int row0 = m0 + wm * 32 + mf * 16 + g * 4;
      const int col  = n0 + wn * 32 + nf * 16 + r15;
      float vv[4];
      #pragma unroll
      for (int r = 0; r < 4; ++r)
        vv[r] = (acc[mf][nf][r] + srow[row0 + r] * bias[col]) * scale;
      if (!half){
        #pragma unroll
        for (int r = 0; r < 4; ++r)
          pk[b * 131072 + (long)(row0 + r) * 1024 + col] = f2bf(vv[r]);
      } else {
        u32 lo = (u32)f2bf(vv[0]) | ((u32)f2bf(vv[1]) << 16);
        u32 hi = (u32)f2bf(vv[2]) | ((u32)f2bf(vv[3]) << 16);
        u32x2 pk2 = { lo, hi };
        *(u32x2*)(pvT + b * 131072 + (long)col * 128 + row0) = pk2;
      }
    }
  }
}

// ---------------- big GEMM: 256x256 tile, 4-phase/K-tile counted-vmcnt schedule ----
// (R4-ship variant: measured 45.3-46.3 us at this shape — best of the 3 schedules.)
template<int EPI, typename OutT>
__global__ __launch_bounds__(512, 1) void k_gemm256b(
    const u16* __restrict__ A, int lda,
    const u16* __restrict__ B, int ldb,
    OutT* __restrict__ C, int ldc,
    int K, const float* __restrict__ bias)
{
  constexpr int BM = 256, BN = 256, BK = 64;
  __shared__ u16 ldsA[2][BM * BK];
  __shared__ u16 ldsB[2][BN * BK];
  u32 bx, by, bz;
  xcd_remap(bx, by, bz);
  const int m0 = by * BM, n0 = bx * BN;
  const int t = threadIdx.x, lane = t & 63, w = t >> 6;
  const int wm = w >> 2, wn = w & 3;
  const int r15 = lane & 15, g = lane >> 4;
  const int NT = K >> 6;

  auto stA = [&](int buf, int half, int kt){
    #pragma unroll
    for (int j = 0; j < 2; ++j){
      int ch = j * 512 + t, row = ch >> 3, cc = ch & 7;
      gld16(A + (long)(m0 + half * 128 + row) * lda + kt + ((cc ^ (row & 7)) * 8),
            (char*)ldsA[buf] + half * 16384 + ch * 16);
    }
  };
  auto stB = [&](int buf, int half, int kt){
    #pragma unroll
    for (int j = 0; j < 2; ++j){
      int ch = j * 512 + t, row = ch >> 3, cc = ch & 7;
      gld16(B + (long)(n0 + half * 128 + row) * ldb + kt + ((cc ^ (row & 7)) * 8),
            (char*)ldsB[buf] + half * 16384 + ch * 16);
    }
  };

  // prologue: tile0 fully (8 loads), then Blo1,Bhi1,Alo1 (6 loads)
  stB(0,0,0); stB(0,1,0); stA(0,0,0); stA(0,1,0);
  if (NT > 1){ stB(1,0,BK); stB(1,1,BK); stA(1,0,BK); }
  asm volatile("s_waitcnt vmcnt(6)" ::: "memory");
  __builtin_amdgcn_s_barrier();
  asm volatile("" ::: "memory");

  fx4 acc[8][4] = {};
  for (int tt = 0; tt < NT; ++tt){
    const int buf = tt & 1;
    bf16x8 a[2][4], b01[2][2], b23[2][2];
    // ---------- phase 1: read A(mf0-3)+B01; stage A-hi(t+1); MFMA Q(0-3,0-1)
    #pragma unroll
    for (int ks = 0; ks < 2; ++ks)
      #pragma unroll
      for (int mf = 0; mf < 4; ++mf){
        int row = wm * 128 + mf * 16 + r15;
        a[ks][mf] = *(const bf16x8*)((const char*)ldsA[buf] + row * 128 + (((ks*4+g) ^ (r15 & 7)) * 16));
      }
    #pragma unroll
    for (int ks = 0; ks < 2; ++ks)
      #pragma unroll
      for (int nf = 0; nf < 2; ++nf){
        int row = wn * 64 + nf * 16 + r15;
        b01[ks][nf] = *(const bf16x8*)((const char*)ldsB[buf] + row * 128 + (((ks*4+g) ^ (r15 & 7)) * 16));
      }
    if (tt + 1 < NT) stA(buf ^ 1, 1, (tt + 1) * BK);
    __builtin_amdgcn_s_setprio(1);
    #pragma unroll
    for (int ks = 0; ks < 2; ++ks)
      #pragma unroll
      for (int mf = 0; mf < 4; ++mf)
        #pragma unroll
        for (int nf = 0; nf < 2; ++nf)
          acc[mf][nf] = __builtin_amdgcn_mfma_f32_16x16x32_bf16(a[ks][mf], b01[ks][nf], acc[mf][nf], 0, 0, 0);
    __builtin_amdgcn_s_setprio(0);
    asm volatile("" ::: "memory");
    __builtin_amdgcn_s_barrier();
    asm volatile("" ::: "memory");
    // ---------- phase 2: read B23; MFMA Q(0-3,2-3)
    #pragma unroll
    for (int ks = 0; ks < 2; ++ks)
      #pragma unroll
      for (int nf = 0; nf < 2; ++nf){
        int row = wn * 64 + (nf + 2) * 16 + r15;
        b23[ks][nf] = *(const bf16x8*)((const char*)ldsB[buf] + row * 128 + (((ks*4+g) ^ (r15 & 7)) * 16));
      }
    __builtin_amdgcn_s_setprio(1);
    #pragma unroll
    for (int ks = 0; ks < 2; ++ks)
      #pragma unroll
      for (int mf = 0; mf < 4; ++mf)
        #pragma unroll
        for (int nf = 0; nf < 2; ++nf)
          acc[mf][nf + 2] = __builtin_amdgcn_mfma_f32_16x16x32_bf16(a[ks][mf], b23[ks][nf], acc[mf][nf + 2], 0, 0, 0);
    __builtin_amdgcn_s_setprio(0);
    asm volatile("" ::: "memory");
    __builtin_amdgcn_s_barrier();
    asm volatile("" ::: "memory");
    // ---------- phase 3: read A(mf4-7); stage B-lo(t+2); MFMA Q(4-7,2-3)
    #pragma unroll
    for (int ks = 0; ks < 2; ++ks)
      #pragma unroll
      for (int mf = 0; mf < 4; ++mf){
        int row = wm * 128 + (mf + 4) * 16 + r15;
        a[ks][mf] = *(const bf16x8*)((const char*)ldsA[buf] + row * 128 + (((ks*4+g) ^ (r15 & 7)) * 16));
      }
    if (tt + 2 < NT) stB(buf, 0, (tt + 2) * BK);
    __builtin_amdgcn_s_setprio(1);
    #pragma unroll
    for (int ks = 0; ks < 2; ++ks)
      #pragma unroll
      for (int mf = 0; mf < 4; ++mf)
        #pragma unroll
        for (int nf = 0; nf < 2; ++nf)
          acc[mf + 4][nf + 2] = __builtin_amdgcn_mfma_f32_16x16x32_bf16(a[ks][mf], b23[ks][nf], acc[mf + 4][nf + 2], 0, 0, 0);
    __builtin_amdgcn_s_setprio(0);
    asm volatile("" ::: "memory");
    __builtin_amdgcn_s_barrier();
    asm volatile("" ::: "memory");
    // ---------- phase 4: stage A-lo(t+2)+B-hi(t+2); MFMA Q(4-7,0-1); counted wait
    if (tt + 2 < NT){ stA(buf, 0, (tt + 2) * BK); stB(buf, 1, (tt + 2) * BK); }
    __builtin_amdgcn_s_setprio(1);
    #pragma unroll
    for (int ks = 0; ks < 2; ++ks)
      #pragma unroll
      for (int mf = 0; mf < 4; ++mf)
        #pragma unroll
        for (int nf = 0; nf < 2; ++nf)
          acc[mf + 4][nf] = __builtin_amdgcn_mfma_f32_16x16x32_bf16(a[ks][mf], b01[ks][nf], acc[mf + 4][nf], 0, 0, 0);
    __builtin_amdgcn_s_setprio(0);
    if (tt + 2 < NT)      { asm volatile("s_waitcnt vmcnt(6)" ::: "memory"); }
    else if (tt + 1 < NT) { asm volatile("s_waitcnt vmcnt(0)" ::: "memory"); }
    asm volatile("" ::: "memory");
    __builtin_amdgcn_s_barrier();
    asm volatile("" ::: "memory");
  }

  #pragma unroll
  for (int mf = 0; mf < 8; ++mf)
    #pragma unroll
    for (int nf = 0; nf < 4; ++nf){
      const int row0 = m0 + wm * 128 + mf * 16 + g * 4;
      const int col  = n0 + wn * 64 + nf * 16 + r15;
      float bcol = 0.f;
      if constexpr (EPI == 1) bcol = bias[col];
      #pragma unroll
      for (int r = 0; r < 4; ++r){
        float vv = acc[mf][nf][r] + bcol;
        if constexpr (sizeof(OutT) == 2) C[(long)(row0 + r) * ldc + col] = (OutT)f2bf(vv);
        else                             C[(long)(row0 + r) * ldc + col] = (OutT)vv;
      }
    }
}

// ---------------- fused attention, pass 1: partial Z over an n-half ----------------
// grid (2,128): bx = n-half, by = z. Writes zpart[bx][z][128] (no reciprocal).
__global__ __launch_bounds__(512) void k_stats(const u16* __restrict__ pk,
                                               const u16* __restrict__ qp,
                                               float* __restrict__ zpart){
  const int hf = blockIdx.x, z = blockIdx.y;
  const int b = z >> 4, h = z & 15;
  const u16* pkh = pk + b * 131072 + h * 64;
  const u16* qph = qp + (long)z * 131072;
  __shared__ u16 pkL[128 * 64];
  __shared__ float zred[8][128];
  const int t = threadIdx.x, lane = t & 63, w = t >> 6;
  const int r15 = lane & 15, g = lane >> 4;
  #pragma unroll
  for (int i = 0; i < 2; ++i){
    int ch = i * 512 + t, row = ch >> 3, cc = ch & 7;
    int csrc = cc ^ (row & 7);
    gld16(pkh + (long)row * 1024 + csrc * 8, (char*)pkL + ch * 16);
  }
  __syncthreads();
  float zacc[8][4] = {};
  for (int c = 0; c < 4; ++c){
    const int n0 = hf * 1024 + w * 128 + c * 32;
    fx4 acc[8][2] = {};
    #pragma unroll
    for (int ks = 0; ks < 2; ++ks){
      bf16x8 bq[2];
      #pragma unroll
      for (int nf = 0; nf < 2; ++nf)
        bq[nf] = *(const bf16x8*)(qph + (long)(n0 + nf * 16 + r15) * 64 + ks * 32 + g * 8);
      #pragma unroll
      for (int mf = 0; mf < 8; ++mf){
        int row = mf * 16 + r15;
        int x = (ks * 4 + g) ^ (row & 7);
        bf16x8 a = *(const bf16x8*)((const char*)pkL + row * 128 + x * 16);
        #pragma unroll
        for (int nf = 0; nf < 2; ++nf)
          acc[mf][nf] = __builtin_amdgcn_mfma_f32_16x16x32_bf16(a, bq[nf], acc[mf][nf], 0, 0, 0);
      }
    }
    #pragma unroll
    for (int mf = 0; mf < 8; ++mf)
      #pragma unroll
      for (int nf = 0; nf < 2; ++nf)
        #pragma unroll
        for (int r = 0; r < 4; ++r)
          zacc[mf][r] += __expf(acc[mf][nf][r]);
  }
  #pragma unroll
  for (int mf = 0; mf < 8; ++mf)
    #pragma unroll
    for (int r = 0; r < 4; ++r){
      float v = zacc[mf][r];
      v += __shfl_xor(v, 1); v += __shfl_xor(v, 2);
      v += __shfl_xor(v, 4); v += __shfl_xor(v, 8);
      zacc[mf][r] = v;
    }
  if (r15 == 0){
    #pragma unroll
    for (int mf = 0; mf < 8; ++mf)
      #pragma unroll
      for (int r = 0; r < 4; ++r)
        zred[w][mf * 16 + g * 4 + r] = zacc[mf][r];
  }
  __syncthreads();
  if (t < 128){
    float s = 0.f;
    #pragma unroll
    for (int w2 = 0; w2 < 8; ++w2) s += zred[w2][t];
    zpart[hf * 16384 + (long)z * 128 + t] = s;
  }
}

// ---------------- fused attention, pass 2: out = attn^T @ pv ----------------
__global__ __launch_bounds__(256) void k_attn(const u16* __restrict__ pk,
                                              const u16* __restrict__ qp,
                                              const u16* __restrict__ pvT,
                                              const float* __restrict__ zpart,
                                              u16* __restrict__ outh){
  u32 bx, by, bz;
  xcd_remap(bx, by, bz);
  const int z = by, nb = bx;
  const int b = z >> 4, h = z & 15;
  const u16* pkh = pk  + b * 131072 + h * 64;
  const u16* qph = qp  + (long)z * 131072;
  const u16* pvh = pvT + b * 131072 + h * 8192;
  __shared__ u16 pkL[128 * 64];
  __shared__ u16 ptL[4][32 * 132];
  __shared__ float zL[128];
  const int t = threadIdx.x, lane = t & 63, w = t >> 6;
  const int r15 = lane & 15, g = lane >> 4;
  #pragma unroll
  for (int i = 0; i < 4; ++i){
    int ch = i * 256 + t, row = ch >> 3, cc = ch & 7;
    int csrc = cc ^ (row & 7);
    gld16(pkh + (long)row * 1024 + csrc * 8, (char*)pkL + ch * 16);
  }
  if (t < 128)
    zL[t] = 1.0f / (zpart[(long)z * 128 + t] + zpart[16384 + (long)z * 128 + t]);
  __syncthreads();
  const int n0 = nb * 128 + w * 32;
  fx4 acc[8][2] = {};
  #pragma unroll
  for (int ks = 0; ks < 2; ++ks){
    bf16x8 bq[2];
    #pragma unroll
    for (int nf = 0; nf < 2; ++nf)
      bq[nf] = *(const bf16x8*)(qph + (long)(n0 + nf * 16 + r15) * 64 + ks * 32 + g * 8);
    #pragma unroll
    for (int mf = 0; mf < 8; ++mf){
      int row = mf * 16 + r15;
      int x = (ks * 4 + g) ^ (row & 7);
      bf16x8 a = *(const bf16x8*)((const char*)pkL + row * 128 + x * 16);
      #pragma unroll
      for (int nf = 0; nf < 2; ++nf)
        acc[mf][nf] = __builtin_amdgcn_mfma_f32_16x16x32_bf16(a, bq[nf], acc[mf][nf], 0, 0, 0);
    }
  }
  u16* pt = ptL[w];
  #pragma unroll
  for (int mf = 0; mf < 8; ++mf){
    const int kb = mf * 16 + g * 4;
    const float z0 = zL[kb], z1 = zL[kb + 1], z2 = zL[kb + 2], z3 = zL[kb + 3];
    #pragma unroll
    for (int nf = 0; nf < 2; ++nf){
      const int nl = nf * 16 + r15;
      u32 lo = (u32)f2bf(__expf(acc[mf][nf][0]) * z0) |
               ((u32)f2bf(__expf(acc[mf][nf][1]) * z1) << 16);
      u32 hi = (u32)f2bf(__expf(acc[mf][nf][2]) * z2) |
               ((u32)f2bf(__expf(acc[mf][nf][3]) * z3) << 16);
      u32x2 pkd = { lo, hi };
      *(u32x2*)(pt + nl * 132 + kb) = pkd;
    }
  }
  fx4 o[2][4] = {};
  #pragma unroll
  for (int ks = 0; ks < 4; ++ks){
    bf16x8 bv[4];
    #pragma unroll
    for (int nf = 0; nf < 4; ++nf)
      bv[nf] = *(const bf16x8*)(pvh + (long)(nf * 16 + r15) * 128 + ks * 32 + g * 8);
    #pragma unroll
    for (int mf = 0; mf < 2; ++mf){
      bf16x8 pa = *(const bf16x8*)(pt + (mf * 16 + r15) * 132 + ks * 32 + g * 8);
      #pragma unroll
      for (int nf = 0; nf < 4; ++nf)
        o[mf][nf] = __builtin_amdgcn_mfma_f32_16x16x32_bf16(pa, bv[nf], o[mf][nf], 0, 0, 0);
    }
  }
  u16* og = outh + ((long)b * 2048 + n0) * 1024 + h * 64;
  #pragma unroll
  for (int mf = 0; mf < 2; ++mf)
    #pragma unroll
    for (int nf = 0; nf < 4; ++nf)
      #pragma unroll
      for (int r = 0; r < 4; ++r){
        int nl = mf * 16 + g * 4 + r;
        og[(long)nl * 1024 + nf * 16 + r15] = f2bf(o[mf][nf][r]);
      }
}

extern "C" void kernel_launch(void* const* d_in, const int* in_sizes, int n_in,
                              void* d_out, int out_size, void* d_ws, size_t ws_size,
                              hipStream_t stream)
{
  const float* q   = (const float*)d_in[0];
  const float* k   = (const float*)d_in[1];
  const float* v   = (const float*)d_in[2];
  const float* Wq  = (const float*)d_in[3];
  const float* bq  = (const float*)d_in[4];
  const float* Wk  = (const float*)d_in[5];
  const float* bk  = (const float*)d_in[6];
  const float* Wv  = (const float*)d_in[7];
  const float* bv  = (const float*)d_in[8];
  const float* pjk = (const float*)d_in[9];
  const float* pjv = (const float*)d_in[10];
  const float* Wo  = (const float*)d_in[11];
  const float* bo  = (const float*)d_in[12];

  if (ws_size < 152044544u) return;

  char* ws = (char*)d_ws;
  u16*  q_bf  = (u16*)(ws + 0);            // 32MB (reused by outh)
  u16*  kT    = (u16*)(ws + 33554432);     // 32MB [1024][2048]/batch (reused by zpart)
  u16*  vT    = (u16*)(ws + 67108864);     // 32MB (contiguous after kT)
  u16*  W_bf  = (u16*)(ws + 100663296);    // 4 x 1Mi elems: Wq,Wk,Wv,Wo
  u16*  projT = (u16*)(ws + 109051904);    // projkT [128][2048], projvT after
  float* sk   = (float*)(ws + 110100480);  // [128] colsum(proj_k); sv right after
  u16*  qp    = (u16*)(ws + 110101504);    // 32MB [16384,1024]
  u16*  ck    = (u16*)(ws + 143655936);    // [2][8][128][1024]
  u16*  pk    = (u16*)(ws + 147850240);    // [8][128][1024], pre-scaled 1/8
  u16*  pvT   = (u16*)(ws + 149947392);    // [8][16][64][128]
  float* zpart = (float*)(ws + 33554432);  // [2][128][128] overlay kT
  u16*  outh  = (u16*)(ws + 0);            // overlay q_bf
  u16*  Wq_bf = W_bf, *Wk_bf = W_bf + 1048576, *Wv_bf = W_bf + 2097152, *Wo_bf = W_bf + 3145728;

  // converts: q + 4 weights in one launch (also zeroes sk/sv)
  k_f2bfAll<<<dim3(128,20), 256, 0, stream>>>(Wq, Wk, Wv, Wo, q, W_bf, q_bf, sk);
  k_tconvP<<<dim3(2,32,2), 256, 0, stream>>>(pjk, pjv, projT, sk);
  k_tconvKV<<<dim3(16,32,16), 256, 0, stream>>>(k, v, kT);

  // qp = q @ Wq^T + bq   (256x256 4-phase kernel)
  k_gemm256b<1,u16><<<dim3(4,64), 512, 0, stream>>>(
      q_bf,1024, Wq_bf,1024, qp,1024, 1024, bq);
  // ck = projkT @ k^T ; cv = projvT @ v^T  (BT layout, 128x64 tile, 256 blocks)
  k_gemm<128,64,3,0,u16><<<dim3(16,1,16), 256, 0, stream>>>(
      projT,2048,0, kT,2048,0, ck,1024,0, 2048, nullptr, nullptr, 1.f);
  // pk and pvT in one launch
  k_pkpv<<<dim3(16,2,16), 256, 0, stream>>>(ck, Wk_bf, Wv_bf, bk, bv, sk, pk, pvT);
  // fused attention (stats uses all 256 CUs; deterministic two-half sum)
  k_stats<<<dim3(2,128), 512, 0, stream>>>(pk, qp, zpart);
  k_attn<<<dim3(16,128), 256, 0, stream>>>(pk, qp, pvT, zpart, outh);
  // final = outh @ Wo^T + bo -> fp32 d_out
  k_gemm256b<1,float><<<dim3(4,64), 512, 0, stream>>>(
      outh,1024, Wo_bf,1024, (float*)d_out,1024, 1024, bo);
}

// Round 14
// 221.651 us; speedup vs baseline: 1.2063x; 1.2063x over previous
//
#include <hip/hip_runtime.h>

typedef unsigned short u16;
typedef unsigned int   u32;
typedef __attribute__((ext_vector_type(4))) float fx4;
typedef __attribute__((ext_vector_type(8))) __bf16 bf16x8;
typedef __attribute__((ext_vector_type(4))) __bf16 bf16x4;
typedef __attribute__((ext_vector_type(8))) unsigned short us8;
typedef __attribute__((ext_vector_type(2))) unsigned int u32x2;

__device__ __forceinline__ u16 f2bf(float x){
  u32 u = __builtin_bit_cast(u32, x);
  u += 0x7fffu + ((u >> 16) & 1u);
  return (u16)(u >> 16);
}
__device__ __forceinline__ float b2f(u16 h){
  u32 u = ((u32)h) << 16;
  return __builtin_bit_cast(float, u);
}
__device__ __forceinline__ void gld16(const void* g, void* l){
  __builtin_amdgcn_global_load_lds(
      (const __attribute__((address_space(1))) u32*)g,
      (__attribute__((address_space(3))) u32*)l, 16, 0, 0);
}
// XCD-chunked bijective swizzle (grid size must be %8==0).
__device__ __forceinline__ void xcd_remap(u32& bx, u32& by, u32& bz){
  u32 nx = gridDim.x, ny = gridDim.y, nz = gridDim.z;
  u32 nwg = nx * ny * nz;
  u32 orig = (blockIdx.z * ny + blockIdx.y) * nx + blockIdx.x;
  u32 lid = (orig & 7u) * (nwg >> 3) + (orig >> 3);
  bx = lid % nx;
  u32 rem = lid / nx;
  by = rem % ny;
  bz = rem / ny;
}

// ---------------- fp32 -> bf16 convert: 4 weights + q in ONE launch -------------
// y 0..3 -> weight y ; y 4..19 -> q slab (y-4). Also zeroes the 256-float colsum.
__global__ __launch_bounds__(256) void k_f2bfAll(const float* __restrict__ w0,
                                                 const float* __restrict__ w1,
                                                 const float* __restrict__ w2,
                                                 const float* __restrict__ w3,
                                                 const float* __restrict__ q,
                                                 u16* __restrict__ wout,
                                                 u16* __restrict__ qout,
                                                 float* __restrict__ zbuf){
  if (blockIdx.x == 0 && blockIdx.y == 0) zbuf[threadIdx.x] = 0.f;
  const int y = blockIdx.y;
  const float* src;
  u16* dst;
  if (y < 4){
    src = y == 0 ? w0 : y == 1 ? w1 : y == 2 ? w2 : w3;
    dst = wout + (long)y * 1048576;
  } else {
    src = q + (long)(y - 4) * 1048576;
    dst = qout + (long)(y - 4) * 1048576;
  }
  int i = blockIdx.x * 256 + threadIdx.x;
  const int stride = gridDim.x * 256;
  for (; i < 131072; i += stride){
    const float4* p = (const float4*)src + (long)i * 2;
    float4 a = p[0], b = p[1];
    us8 o = { f2bf(a.x), f2bf(a.y), f2bf(a.z), f2bf(a.w),
              f2bf(b.x), f2bf(b.y), f2bf(b.z), f2bf(b.w) };
    *((us8*)dst + i) = o;
  }
}

// ---------------- proj transpose+convert+colsum, one launch (z 0..1) ----------------
__global__ __launch_bounds__(256) void k_tconvP(const float* __restrict__ pjk,
                                                const float* __restrict__ pjv,
                                                u16* __restrict__ projT,
                                                float* __restrict__ ssum){
  const int z = blockIdx.z;
  const float* in = z ? pjv : pjk;
  u16* out = projT + z * 262144;
  float* colsum = ssum + z * 128;
  const int c0 = blockIdx.x * 64, r0 = blockIdx.y * 64;
  __shared__ u16 tile[64][66];
  __shared__ float red[256];
  const int t = threadIdx.x;
  const int cc = t & 63, wq = t >> 6;
  float part = 0.f;
  #pragma unroll
  for (int i = 0; i < 16; ++i){
    int rr = i * 4 + wq;
    float v = in[(long)(r0 + rr) * 128 + c0 + cc];
    tile[rr][cc] = f2bf(v);
    part += v;
  }
  red[t] = part;
  __syncthreads();
  if (t < 64){
    float s = red[t] + red[t + 64] + red[t + 128] + red[t + 192];
    atomicAdd(&colsum[c0 + t], s);
  }
  __syncthreads();
  const int oc0 = t >> 5, jb = (t & 31) * 2;
  #pragma unroll
  for (int i = 0; i < 8; ++i){
    int oc = oc0 + i * 8;
    u32 pk2 = (u32)tile[jb][oc] | ((u32)tile[jb + 1][oc] << 16);
    *(u32*)(out + (long)(c0 + oc) * 2048 + r0 + jb) = pk2;
  }
}

// ---------------- fused transpose ck GEMM v3 (R8-ship, measured 54-55 us) ----------
// ck[p][b][kr][d] = projT[p] @ src[b]^T, src = k|v fp32 [2048 n][1024 d].
// BM=64(kr) BN=64(d) BK=64(n); grid (16,2,16)=512 blocks; LDS 51KB -> 3 blocks/CU.
// Depth-2 pipeline, 3 LDS buffers, counted vmcnt(6), raw s_barrier (no vmcnt(0)
// drain in loop). B transpose-write piece-XOR swizzled: 8B piece r4 of row d stored
// at piece r4^(d&15); read as 2x ds_read_b64 mirrored.
__global__ __launch_bounds__(256) void k_gemmTN(
    const u16* __restrict__ projT, const float* __restrict__ ksrc,
    const float* __restrict__ vsrc, u16* __restrict__ ck)
{
  u32 bx, by, bz; xcd_remap(bx, by, bz);
  const int p = bz >> 3, b = bz & 7;
  const u16* A = projT + p * 262144 + by * 64 * 2048;      // [64 kr][2048 n]
  const float* S = (p ? vsrc : ksrc) + (long)b * 2097152;  // [2048 n][1024 d]
  u16* C = ck + p * 1048576 + b * 131072 + by * 65536;
  const int d0 = bx * 64;
  __shared__ u16 ldsA[3][64 * 64];
  __shared__ u16 ldsB[3][64 * 72];
  const int t = threadIdx.x, lane = t & 63, w = t >> 6;
  const int wm = w >> 1, wn = w & 1;
  const int r15 = lane & 15, g = lane >> 4;
  const int c4 = t & 15, r4 = t >> 4;

  auto ldA = [&](int kt, int buf){
    #pragma unroll
    for (int i = 0; i < 2; ++i){
      int ch = i * 256 + t, row = ch >> 3, cc = ch & 7;
      gld16(A + (long)row * 2048 + kt + ((cc ^ (row & 7)) * 8),
            (char*)ldsA[buf] + ch * 16);
    }
  };
  auto ldS = [&](int kt, float4* f){
    #pragma unroll
    for (int i = 0; i < 4; ++i)
      f[i] = *(const float4*)(S + (long)(kt + r4 * 4 + i) * 1024 + d0 + c4 * 4);
  };
  auto wrB = [&](const float4* f, int buf){
    #pragma unroll
    for (int j = 0; j < 4; ++j){
      const int d = c4 * 4 + j;
      u32 lo = (u32)f2bf(((const float*)&f[0])[j]) | ((u32)f2bf(((const float*)&f[1])[j]) << 16);
      u32 hi = (u32)f2bf(((const float*)&f[2])[j]) | ((u32)f2bf(((const float*)&f[3])[j]) << 16);
      u32x2 pr = { lo, hi };
      *(u32x2*)&ldsB[buf][d * 72 + ((r4 ^ (d & 15)) * 4)] = pr;
    }
  };

  fx4 acc[2][2] = {};
  auto compute = [&](int buf){
    #pragma unroll
    for (int ks = 0; ks < 2; ++ks){
      bf16x8 af[2], bfv[2];
      #pragma unroll
      for (int mf = 0; mf < 2; ++mf){
        int row = wm * 32 + mf * 16 + r15;
        af[mf] = *(const bf16x8*)((const char*)ldsA[buf] + row * 128 +
                                  (((ks * 4 + g) ^ (row & 7)) * 16));
      }
      #pragma unroll
      for (int nf = 0; nf < 2; ++nf){
        const int d = wn * 32 + nf * 16 + r15, x = d & 15;
        const int q0 = ks * 8 + g * 2;
        bf16x4 lo = *(const bf16x4*)&ldsB[buf][d * 72 + ((q0 ^ x) * 4)];
        bf16x4 hi = *(const bf16x4*)&ldsB[buf][d * 72 + (((q0 + 1) ^ x) * 4)];
        bfv[nf] = __builtin_shufflevector(lo, hi, 0, 1, 2, 3, 4, 5, 6, 7);
      }
      #pragma unroll
      for (int mf = 0; mf < 2; ++mf)
        #pragma unroll
        for (int nf = 0; nf < 2; ++nf)
          acc[mf][nf] = __builtin_amdgcn_mfma_f32_16x16x32_bf16(af[mf], bfv[nf], acc[mf][nf], 0, 0, 0);
    }
  };

  float4 fa[4], fb[4];
  ldS(0, fa); ldA(0, 0);
  ldS(64, fb); ldA(64, 1);
  asm volatile("s_waitcnt vmcnt(6)" ::: "memory");  // fa's 4 + A0's 2 landed
  wrB(fa, 0);
  asm volatile("s_waitcnt lgkmcnt(0)" ::: "memory");
  __builtin_amdgcn_s_barrier();
  asm volatile("" ::: "memory");

  for (int tt = 0; tt < 32; tt += 2){
    { // phase E: compute tile tt; prefetch tt+2 into fa; publish tt+1 (fb)
      const bool pf = (tt + 2 < 32);
      if (pf){ ldS((tt + 2) * 64, fa); ldA((tt + 2) * 64, (tt + 2) % 3); }
      asm volatile("" ::: "memory");
      compute(tt % 3);
      if (pf) { asm volatile("s_waitcnt vmcnt(6)" ::: "memory"); }
      else    { asm volatile("s_waitcnt vmcnt(0)" ::: "memory"); }
      wrB(fb, (tt + 1) % 3);
      asm volatile("s_waitcnt lgkmcnt(0)" ::: "memory");
      __builtin_amdgcn_s_barrier();
      asm volatile("" ::: "memory");
    }
    { // phase O: compute tile tt+1; prefetch tt+3 into fb; publish tt+2 (fa)
      const bool pf = (tt + 3 < 32);
      const bool hv = (tt + 2 < 32);
      if (pf){ ldS((tt + 3) * 64, fb); ldA((tt + 3) * 64, (tt + 3) % 3); }
      asm volatile("" ::: "memory");
      compute((tt + 1) % 3);
      if (hv){
        if (pf) { asm volatile("s_waitcnt vmcnt(6)" ::: "memory"); }
        else    { asm volatile("s_waitcnt vmcnt(0)" ::: "memory"); }
        wrB(fa, (tt + 2) % 3);
      }
      asm volatile("s_waitcnt lgkmcnt(0)" ::: "memory");
      __builtin_amdgcn_s_barrier();
      asm volatile("" ::: "memory");
    }
  }

  #pragma unroll
  for (int mf = 0; mf < 2; ++mf)
    #pragma unroll
    for (int nf = 0; nf < 2; ++nf){
      const int row0 = wm * 32 + mf * 16 + g * 4;
      const int col  = d0 + wn * 32 + nf * 16 + r15;
      #pragma unroll
      for (int r = 0; r < 4; ++r)
        C[(long)(row0 + r) * 1024 + col] = f2bf(acc[mf][nf][r]);
    }
}

// ---------------- merged pk / pvT GEMM (z<8: pk EPI2 ; z>=8: pvT EPI3) ----------------
__global__ __launch_bounds__(256) void k_pkpv(
    const u16* __restrict__ ck, const u16* __restrict__ Wk_bf,
    const u16* __restrict__ Wv_bf, const float* __restrict__ bk,
    const float* __restrict__ bv, const float* __restrict__ ssum,
    u16* __restrict__ pk, u16* __restrict__ pvT)
{
  constexpr int BM = 64, BN = 64, BK = 64;
  __shared__ u16 ldsA[BM * BK];
  __shared__ u16 ldsB[BN * BK];
  u32 bx, by, bz;
  xcd_remap(bx, by, bz);
  const int half = bz >> 3, b = bz & 7;
  const u16* A = ck + half * 1048576 + b * 131072;
  const u16* B = half ? Wv_bf : Wk_bf;
  const float* bias = half ? bv : bk;
  const float* srow = ssum + half * 128;
  const float scale = half ? 1.f : 0.125f;
  const int t = threadIdx.x;
  const int lane = t & 63;
  const int w = t >> 6, wm = w >> 1, wn = w & 1;
  const int r15 = lane & 15, g = lane >> 4;
  const int m0 = by * BM, n0 = bx * BN;
  fx4 acc[2][2] = {};
  for (int kt = 0; kt < 1024; kt += BK){
    #pragma unroll
    for (int i = 0; i < 2; ++i){
      int ch = i * 256 + t, row = ch >> 3, cc = ch & 7;
      gld16(A + (long)(m0 + row) * 1024 + kt + cc * 8, (char*)ldsA + ch * 16);
    }
    #pragma unroll
    for (int i = 0; i < 2; ++i){
      int ch = i * 256 + t, row = ch >> 3, cc = ch & 7;
      gld16(B + (long)(n0 + row) * 1024 + kt + cc * 8, (char*)ldsB + ch * 16);
    }
    __syncthreads();
    #pragma unroll
    for (int ks = 0; ks < 2; ++ks){
      bf16x8 af[2], bfv[2];
      #pragma unroll
      for (int mf = 0; mf < 2; ++mf)
        af[mf] = *(const bf16x8*)&ldsA[(wm * 32 + mf * 16 + r15) * BK + ks * 32 + g * 8];
      #pragma unroll
      for (int nf = 0; nf < 2; ++nf)
        bfv[nf] = *(const bf16x8*)&ldsB[(wn * 32 + nf * 16 + r15) * BK + ks * 32 + g * 8];
      #pragma unroll
      for (int mf = 0; mf < 2; ++mf)
        #pragma unroll
        for (int nf = 0; nf < 2; ++nf)
          acc[mf][nf] = __builtin_amdgcn_mfma_f32_16x16x32_bf16(af[mf], bfv[nf], acc[mf][nf], 0, 0, 0);
    }
    __syncthreads();
  }
  #pragma unroll
  for (int mf = 0; mf < 2; ++mf){
    #pragma unroll
    for (int nf = 0; nf < 2; ++nf){
      const int row0 = m0 + wm * 32 + mf * 16 + g * 4;
      const int col  = n0 + wn * 32 + nf * 16 + r15;
      float vv[4];
      #pragma unroll
      for (int r = 0; r < 4; ++r)
        vv[r] = (acc[mf][nf][r] + srow[row0 + r] * bias[col]) * scale;
      if (!half){
        #pragma unroll
        for (int r = 0; r < 4; ++r)
          pk[b * 131072 + (long)(row0 + r) * 1024 + col] = f2bf(vv[r]);
      } else {
        u32 lo = (u32)f2bf(vv[0]) | ((u32)f2bf(vv[1]) << 16);
        u32 hi = (u32)f2bf(vv[2]) | ((u32)f2bf(vv[3]) << 16);
        u32x2 pk2 = { lo, hi };
        *(u32x2*)(pvT + b * 131072 + (long)col * 128 + row0) = pk2;
      }
    }
  }
}

// ---------------- big GEMM: 256x256 tile, 4-phase/K-tile counted-vmcnt schedule ----
template<int EPI, typename OutT>
__global__ __launch_bounds__(512, 1) void k_gemm256b(
    const u16* __restrict__ A, int lda,
    const u16* __restrict__ B, int ldb,
    OutT* __restrict__ C, int ldc,
    int K, const float* __restrict__ bias)
{
  constexpr int BM = 256, BN = 256, BK = 64;
  __shared__ u16 ldsA[2][BM * BK];
  __shared__ u16 ldsB[2][BN * BK];
  u32 bx, by, bz;
  xcd_remap(bx, by, bz);
  const int m0 = by * BM, n0 = bx * BN;
  const int t = threadIdx.x, lane = t & 63, w = t >> 6;
  const int wm = w >> 2, wn = w & 3;
  const int r15 = lane & 15, g = lane >> 4;
  const int NT = K >> 6;

  auto stA = [&](int buf, int half, int kt){
    #pragma unroll
    for (int j = 0; j < 2; ++j){
      int ch = j * 512 + t, row = ch >> 3, cc = ch & 7;
      gld16(A + (long)(m0 + half * 128 + row) * lda + kt + ((cc ^ (row & 7)) * 8),
            (char*)ldsA[buf] + half * 16384 + ch * 16);
    }
  };
  auto stB = [&](int buf, int half, int kt){
    #pragma unroll
    for (int j = 0; j < 2; ++j){
      int ch = j * 512 + t, row = ch >> 3, cc = ch & 7;
      gld16(B + (long)(n0 + half * 128 + row) * ldb + kt + ((cc ^ (row & 7)) * 8),
            (char*)ldsB[buf] + half * 16384 + ch * 16);
    }
  };

  stB(0,0,0); stB(0,1,0); stA(0,0,0); stA(0,1,0);
  if (NT > 1){ stB(1,0,BK); stB(1,1,BK); stA(1,0,BK); }
  asm volatile("s_waitcnt vmcnt(6)" ::: "memory");
  __builtin_amdgcn_s_barrier();
  asm volatile("" ::: "memory");

  fx4 acc[8][4] = {};
  for (int tt = 0; tt < NT; ++tt){
    const int buf = tt & 1;
    bf16x8 a[2][4], b01[2][2], b23[2][2];
    // ---------- phase 1
    #pragma unroll
    for (int ks = 0; ks < 2; ++ks)
      #pragma unroll
      for (int mf = 0; mf < 4; ++mf){
        int row = wm * 128 + mf * 16 + r15;
        a[ks][mf] = *(const bf16x8*)((const char*)ldsA[buf] + row * 128 + (((ks*4+g) ^ (r15 & 7)) * 16));
      }
    #pragma unroll
    for (int ks = 0; ks < 2; ++ks)
      #pragma unroll
      for (int nf = 0; nf < 2; ++nf){
        int row = wn * 64 + nf * 16 + r15;
        b01[ks][nf] = *(const bf16x8*)((const char*)ldsB[buf] + row * 128 + (((ks*4+g) ^ (r15 & 7)) * 16));
      }
    if (tt + 1 < NT) stA(buf ^ 1, 1, (tt + 1) * BK);
    __builtin_amdgcn_s_setprio(1);
    #pragma unroll
    for (int ks = 0; ks < 2; ++ks)
      #pragma unroll
      for (int mf = 0; mf < 4; ++mf)
        #pragma unroll
        for (int nf = 0; nf < 2; ++nf)
          acc[mf][nf] = __builtin_amdgcn_mfma_f32_16x16x32_bf16(a[ks][mf], b01[ks][nf], acc[mf][nf], 0, 0, 0);
    __builtin_amdgcn_s_setprio(0);
    asm volatile("" ::: "memory");
    __builtin_amdgcn_s_barrier();
    asm volatile("" ::: "memory");
    // ---------- phase 2
    #pragma unroll
    for (int ks = 0; ks < 2; ++ks)
      #pragma unroll
      for (int nf = 0; nf < 2; ++nf){
        int row = wn * 64 + (nf + 2) * 16 + r15;
        b23[ks][nf] = *(const bf16x8*)((const char*)ldsB[buf] + row * 128 + (((ks*4+g) ^ (r15 & 7)) * 16));
      }
    __builtin_amdgcn_s_setprio(1);
    #pragma unroll
    for (int ks = 0; ks < 2; ++ks)
      #pragma unroll
      for (int mf = 0; mf < 4; ++mf)
        #pragma unroll
        for (int nf = 0; nf < 2; ++nf)
          acc[mf][nf + 2] = __builtin_amdgcn_mfma_f32_16x16x32_bf16(a[ks][mf], b23[ks][nf], acc[mf][nf + 2], 0, 0, 0);
    __builtin_amdgcn_s_setprio(0);
    asm volatile("" ::: "memory");
    __builtin_amdgcn_s_barrier();
    asm volatile("" ::: "memory");
    // ---------- phase 3
    #pragma unroll
    for (int ks = 0; ks < 2; ++ks)
      #pragma unroll
      for (int mf = 0; mf < 4; ++mf){
        int row = wm * 128 + (mf + 4) * 16 + r15;
        a[ks][mf] = *(const bf16x8*)((const char*)ldsA[buf] + row * 128 + (((ks*4+g) ^ (r15 & 7)) * 16));
      }
    if (tt + 2 < NT) stB(buf, 0, (tt + 2) * BK);
    __builtin_amdgcn_s_setprio(1);
    #pragma unroll
    for (int ks = 0; ks < 2; ++ks)
      #pragma unroll
      for (int mf = 0; mf < 4; ++mf)
        #pragma unroll
        for (int nf = 0; nf < 2; ++nf)
          acc[mf + 4][nf + 2] = __builtin_amdgcn_mfma_f32_16x16x32_bf16(a[ks][mf], b23[ks][nf], acc[mf + 4][nf + 2], 0, 0, 0);
    __builtin_amdgcn_s_setprio(0);
    asm volatile("" ::: "memory");
    __builtin_amdgcn_s_barrier();
    asm volatile("" ::: "memory");
    // ---------- phase 4
    if (tt + 2 < NT){ stA(buf, 0, (tt + 2) * BK); stB(buf, 1, (tt + 2) * BK); }
    __builtin_amdgcn_s_setprio(1);
    #pragma unroll
    for (int ks = 0; ks < 2; ++ks)
      #pragma unroll
      for (int mf = 0; mf < 4; ++mf)
        #pragma unroll
        for (int nf = 0; nf < 2; ++nf)
          acc[mf + 4][nf] = __builtin_amdgcn_mfma_f32_16x16x32_bf16(a[ks][mf], b01[ks][nf], acc[mf + 4][nf], 0, 0, 0);
    __builtin_amdgcn_s_setprio(0);
    if (tt + 2 < NT)      { asm volatile("s_waitcnt vmcnt(6)" ::: "memory"); }
    else if (tt + 1 < NT) { asm volatile("s_waitcnt vmcnt(0)" ::: "memory"); }
    asm volatile("" ::: "memory");
    __builtin_amdgcn_s_barrier();
    asm volatile("" ::: "memory");
  }

  #pragma unroll
  for (int mf = 0; mf < 8; ++mf)
    #pragma unroll
    for (int nf = 0; nf < 4; ++nf){
      const int row0 = m0 + wm * 128 + mf * 16 + g * 4;
      const int col  = n0 + wn * 64 + nf * 16 + r15;
      float bcol = 0.f;
      if constexpr (EPI == 1) bcol = bias[col];
      #pragma unroll
      for (int r = 0; r < 4; ++r){
        float vv = acc[mf][nf][r] + bcol;
        if constexpr (sizeof(OutT) == 2) C[(long)(row0 + r) * ldc + col] = (OutT)f2bf(vv);
        else                             C[(long)(row0 + r) * ldc + col] = (OutT)vv;
      }
    }
}

// ---------------- fused attention, pass 1: partial Z over an n-half ----------------
__global__ __launch_bounds__(512) void k_stats(const u16* __restrict__ pk,
                                               const u16* __restrict__ qp,
                                               float* __restrict__ zpart){
  const int hf = blockIdx.x, z = blockIdx.y;
  const int b = z >> 4, h = z & 15;
  const u16* pkh = pk + b * 131072 + h * 64;
  const u16* qph = qp + (long)z * 131072;
  __shared__ u16 pkL[128 * 64];
  __shared__ float zred[8][128];
  const int t = threadIdx.x, lane = t & 63, w = t >> 6;
  const int r15 = lane & 15, g = lane >> 4;
  #pragma unroll
  for (int i = 0; i < 2; ++i){
    int ch = i * 512 + t, row = ch >> 3, cc = ch & 7;
    int csrc = cc ^ (row & 7);
    gld16(pkh + (long)row * 1024 + csrc * 8, (char*)pkL + ch * 16);
  }
  __syncthreads();
  float zacc[8][4] = {};
  for (int c = 0; c < 4; ++c){
    const int n0 = hf * 1024 + w * 128 + c * 32;
    fx4 acc[8][2] = {};
    #pragma unroll
    for (int ks = 0; ks < 2; ++ks){
      bf16x8 bq[2];
      #pragma unroll
      for (int nf = 0; nf < 2; ++nf)
        bq[nf] = *(const bf16x8*)(qph + (long)(n0 + nf * 16 + r15) * 64 + ks * 32 + g * 8);
      #pragma unroll
      for (int mf = 0; mf < 8; ++mf){
        int row = mf * 16 + r15;
        int x = (ks * 4 + g) ^ (row & 7);
        bf16x8 a = *(const bf16x8*)((const char*)pkL + row * 128 + x * 16);
        #pragma unroll
        for (int nf = 0; nf < 2; ++nf)
          acc[mf][nf] = __builtin_amdgcn_mfma_f32_16x16x32_bf16(a, bq[nf], acc[mf][nf], 0, 0, 0);
      }
    }
    #pragma unroll
    for (int mf = 0; mf < 8; ++mf)
      #pragma unroll
      for (int nf = 0; nf < 2; ++nf)
        #pragma unroll
        for (int r = 0; r < 4; ++r)
          zacc[mf][r] += __expf(acc[mf][nf][r]);
  }
  #pragma unroll
  for (int mf = 0; mf < 8; ++mf)
    #pragma unroll
    for (int r = 0; r < 4; ++r){
      float v = zacc[mf][r];
      v += __shfl_xor(v, 1); v += __shfl_xor(v, 2);
      v += __shfl_xor(v, 4); v += __shfl_xor(v, 8);
      zacc[mf][r] = v;
    }
  if (r15 == 0){
    #pragma unroll
    for (int mf = 0; mf < 8; ++mf)
      #pragma unroll
      for (int r = 0; r < 4; ++r)
        zred[w][mf * 16 + g * 4 + r] = zacc[mf][r];
  }
  __syncthreads();
  if (t < 128){
    float s = 0.f;
    #pragma unroll
    for (int w2 = 0; w2 < 8; ++w2) s += zred[w2][t];
    zpart[hf * 16384 + (long)z * 128 + t] = s;
  }
}

// ---------------- fused attention, pass 2: out = attn^T @ pv ----------------
__global__ __launch_bounds__(256) void k_attn(const u16* __restrict__ pk,
                                              const u16* __restrict__ qp,
                                              const u16* __restrict__ pvT,
                                              const float* __restrict__ zpart,
                                              u16* __restrict__ outh){
  u32 bx, by, bz;
  xcd_remap(bx, by, bz);
  const int z = by, nb = bx;
  const int b = z >> 4, h = z & 15;
  const u16* pkh = pk  + b * 131072 + h * 64;
  const u16* qph = qp  + (long)z * 131072;
  const u16* pvh = pvT + b * 131072 + h * 8192;
  __shared__ u16 pkL[128 * 64];
  __shared__ u16 ptL[4][32 * 132];
  __shared__ float zL[128];
  const int t = threadIdx.x, lane = t & 63, w = t >> 6;
  const int r15 = lane & 15, g = lane >> 4;
  #pragma unroll
  for (int i = 0; i < 4; ++i){
    int ch = i * 256 + t, row = ch >> 3, cc = ch & 7;
    int csrc = cc ^ (row & 7);
    gld16(pkh + (long)row * 1024 + csrc * 8, (char*)pkL + ch * 16);
  }
  if (t < 128)
    zL[t] = 1.0f / (zpart[(long)z * 128 + t] + zpart[16384 + (long)z * 128 + t]);
  __syncthreads();
  const int n0 = nb * 128 + w * 32;
  fx4 acc[8][2] = {};
  #pragma unroll
  for (int ks = 0; ks < 2; ++ks){
    bf16x8 bq[2];
    #pragma unroll
    for (int nf = 0; nf < 2; ++nf)
      bq[nf] = *(const bf16x8*)(qph + (long)(n0 + nf * 16 + r15) * 64 + ks * 32 + g * 8);
    #pragma unroll
    for (int mf = 0; mf < 8; ++mf){
      int row = mf * 16 + r15;
      int x = (ks * 4 + g) ^ (row & 7);
      bf16x8 a = *(const bf16x8*)((const char*)pkL + row * 128 + x * 16);
      #pragma unroll
      for (int nf = 0; nf < 2; ++nf)
        acc[mf][nf] = __builtin_amdgcn_mfma_f32_16x16x32_bf16(a, bq[nf], acc[mf][nf], 0, 0, 0);
    }
  }
  u16* pt = ptL[w];
  #pragma unroll
  for (int mf = 0; mf < 8; ++mf){
    const int kb = mf * 16 + g * 4;
    const float z0 = zL[kb], z1 = zL[kb + 1], z2 = zL[kb + 2], z3 = zL[kb + 3];
    #pragma unroll
    for (int nf = 0; nf < 2; ++nf){
      const int nl = nf * 16 + r15;
      u32 lo = (u32)f2bf(__expf(acc[mf][nf][0]) * z0) |
               ((u32)f2bf(__expf(acc[mf][nf][1]) * z1) << 16);
      u32 hi = (u32)f2bf(__expf(acc[mf][nf][2]) * z2) |
               ((u32)f2bf(__expf(acc[mf][nf][3]) * z3) << 16);
      u32x2 pkd = { lo, hi };
      *(u32x2*)(pt + nl * 132 + kb) = pkd;
    }
  }
  fx4 o[2][4] = {};
  #pragma unroll
  for (int ks = 0; ks < 4; ++ks){
    bf16x8 bv[4];
    #pragma unroll
    for (int nf = 0; nf < 4; ++nf)
      bv[nf] = *(const bf16x8*)(pvh + (long)(nf * 16 + r15) * 128 + ks * 32 + g * 8);
    #pragma unroll
    for (int mf = 0; mf < 2; ++mf){
      bf16x8 pa = *(const bf16x8*)(pt + (mf * 16 + r15) * 132 + ks * 32 + g * 8);
      #pragma unroll
      for (int nf = 0; nf < 4; ++nf)
        o[mf][nf] = __builtin_amdgcn_mfma_f32_16x16x32_bf16(pa, bv[nf], o[mf][nf], 0, 0, 0);
    }
  }
  u16* og = outh + ((long)b * 2048 + n0) * 1024 + h * 64;
  #pragma unroll
  for (int mf = 0; mf < 2; ++mf)
    #pragma unroll
    for (int nf = 0; nf < 4; ++nf)
      #pragma unroll
      for (int r = 0; r < 4; ++r){
        int nl = mf * 16 + g * 4 + r;
        og[(long)nl * 1024 + nf * 16 + r15] = f2bf(o[mf][nf][r]);
      }
}

extern "C" void kernel_launch(void* const* d_in, const int* in_sizes, int n_in,
                              void* d_out, int out_size, void* d_ws, size_t ws_size,
                              hipStream_t stream)
{
  const float* q   = (const float*)d_in[0];
  const float* k   = (const float*)d_in[1];
  const float* v   = (const float*)d_in[2];
  const float* Wq  = (const float*)d_in[3];
  const float* bq  = (const float*)d_in[4];
  const float* Wk  = (const float*)d_in[5];
  const float* bk  = (const float*)d_in[6];
  const float* Wv  = (const float*)d_in[7];
  const float* bv  = (const float*)d_in[8];
  const float* pjk = (const float*)d_in[9];
  const float* pjv = (const float*)d_in[10];
  const float* Wo  = (const float*)d_in[11];
  const float* bo  = (const float*)d_in[12];

  if (ws_size < 152044544u) return;

  char* ws = (char*)d_ws;
  u16*  q_bf  = (u16*)(ws + 0);            // 32MB (reused by outh)
  float* zpart = (float*)(ws + 33554432);  // [2][128][128]
  u16*  W_bf  = (u16*)(ws + 100663296);    // 4 x 1Mi elems: Wq,Wk,Wv,Wo
  u16*  projT = (u16*)(ws + 109051904);    // projkT [128][2048], projvT after
  float* sk   = (float*)(ws + 110100480);  // [128] colsum(proj_k); sv right after
  u16*  qp    = (u16*)(ws + 110101504);    // 32MB [16384,1024]
  u16*  ck    = (u16*)(ws + 143655936);    // [2][8][128][1024]
  u16*  pk    = (u16*)(ws + 147850240);    // [8][128][1024], pre-scaled 1/8
  u16*  pvT   = (u16*)(ws + 149947392);    // [8][16][64][128]
  u16*  outh  = (u16*)(ws + 0);            // overlay q_bf
  u16*  Wq_bf = W_bf, *Wk_bf = W_bf + 1048576, *Wv_bf = W_bf + 2097152, *Wo_bf = W_bf + 3145728;

  // converts: q + 4 weights in one launch (also zeroes sk/sv)
  k_f2bfAll<<<dim3(128,20), 256, 0, stream>>>(Wq, Wk, Wv, Wo, q, W_bf, q_bf, sk);
  k_tconvP<<<dim3(2,32,2), 256, 0, stream>>>(pjk, pjv, projT, sk);

  // qp = q @ Wq^T + bq   (256x256 4-phase kernel)
  k_gemm256b<1,u16><<<dim3(4,64), 512, 0, stream>>>(
      q_bf,1024, Wq_bf,1024, qp,1024, 1024, bq);
  // ck = projkT @ k^T ; cv = projvT @ v^T  (fused transpose GEMM, reads fp32 k/v)
  k_gemmTN<<<dim3(16,2,16), 256, 0, stream>>>(projT, k, v, ck);
  // pk and pvT in one launch
  k_pkpv<<<dim3(16,2,16), 256, 0, stream>>>(ck, Wk_bf, Wv_bf, bk, bv, sk, pk, pvT);
  // fused attention (stats uses all 256 CUs; deterministic two-half sum)
  k_stats<<<dim3(2,128), 512, 0, stream>>>(pk, qp, zpart);
  k_attn<<<dim3(16,128), 256, 0, stream>>>(pk, qp, pvT, zpart, outh);
  // final = outh @ Wo^T + bo -> fp32 d_out
  k_gemm256b<1,float><<<dim3(4,64), 512, 0, stream>>>(
      outh,1024, Wo_bf,1024, (float*)d_out,1024, 1024, bo);
}